// Round 4
// baseline (205.989 us; speedup 1.0000x reference)
//
#include <hip/hip_runtime.h>
#include <hip/hip_bf16.h>

#define BZ 8192
#define PP 1024
#define DD 1024
#define KSEL 8

typedef _Float16 f16;
typedef __attribute__((ext_vector_type(8))) _Float16 f16x8;
typedef __attribute__((ext_vector_type(4))) _Float16 f16x4;
typedef __attribute__((ext_vector_type(4))) float f32x4;

// ws layout:
//   floats [0,1024)      inv-norm keys
//   floats [1024,9216)   inv-norm ppg
//   floats [9216,17408)  per-row top-8 score sum
//   floats [17408,25600) per-row entropy
//   floats [25600,91136) top-8 indices (ints)
//   byte 368640..: f16 A(8192x1024) | f16 B(1024x1024) | f16 C(8192x1024)
#define WS_INVK 0
#define WS_INVP 1024
#define WS_SCORE 9216
#define WS_ENT 17408
#define WS_IDX 25600
#define WS_F16_BYTE 368640ull
#define A16_ELEMS 8388608ull
#define B16_ELEMS 1048576ull

__device__ __forceinline__ void gll16(const void* g, void* l) {
  __builtin_amdgcn_global_load_lds((__attribute__((address_space(1))) void*)g,
                                   (__attribute__((address_space(3))) void*)l, 16, 0, 0);
}

// ---------- Kernel 1: normalize rows -> fp16, store inv norms ---------------
__global__ __launch_bounds__(256) void convert_f16(const float* __restrict__ ppg,
                                                   const float* __restrict__ keys,
                                                   float* __restrict__ ws) {
  f16* A16 = (f16*)((char*)ws + WS_F16_BYTE);
  f16* B16 = A16 + A16_ELEMS;

  int blk = blockIdx.x, t = threadIdx.x;
  const float* src; f16* dst; float* invdst;
  if (blk < PP) {
    src = keys + (size_t)blk * DD; dst = B16 + (size_t)blk * DD;
    invdst = ws + WS_INVK + blk;
  } else {
    int r = blk - PP;
    src = ppg + (size_t)r * DD; dst = A16 + (size_t)r * DD;
    invdst = ws + WS_INVP + r;
  }
  float4 v = ((const float4*)src)[t];
  float x[4] = {v.x, v.y, v.z, v.w};
  float s = x[0]*x[0] + x[1]*x[1] + x[2]*x[2] + x[3]*x[3];
  __shared__ float red[4];
  #pragma unroll
  for (int o = 32; o > 0; o >>= 1) s += __shfl_down(s, o);
  if ((t & 63) == 0) red[t >> 6] = s;
  __syncthreads();
  float tot = red[0] + red[1] + red[2] + red[3];
  float inv = 1.0f / fmaxf(sqrtf(tot), 1e-8f);
  f16x4 h;
  #pragma unroll
  for (int j = 0; j < 4; ++j) h[j] = (_Float16)(x[j] * inv);
  *(f16x4*)(dst + t * 4) = h;
  if (t == 0) *invdst = inv;
}

// ---------- Kernel 2: single-pass fp16 MFMA GEMM -> approx cos (f16) --------
#define LDS_A 0
#define LDS_B 8192

__global__ __launch_bounds__(256, 2) void gemm_f16(const float* __restrict__ ws_ro,
                                                   float* __restrict__ ws_w) {
  const f16* A16 = (const f16*)((const char*)ws_ro + WS_F16_BYTE);
  const f16* B16 = A16 + A16_ELEMS;
  f16* C16 = (f16*)((char*)ws_w + WS_F16_BYTE) + A16_ELEMS + B16_ELEMS;

  __shared__ unsigned short lds[16384];  // 32 KB: A 128x64 f16 | B 128x64 f16

  int t = threadIdx.x;
  int wid = t >> 6, lane = t & 63;
  int lr = lane & 15, lg = lane >> 4;

  // bijective XCD-chunked swizzle: 512 blocks, 8 XCDs, 64 each
  int orig = blockIdx.x;
  int wg = (orig & 7) * 64 + (orig >> 3);
  int bm0 = (wg >> 3) * 128;
  int bn0 = (wg & 7) * 128;
  int wm = wid >> 1, wn = wid & 1;  // 2x2 waves, each 64x64

  size_t offA[4], offB[4];
  int ldso[4];
  #pragma unroll
  for (int r = 0; r < 4; ++r) {
    int s = r * 256 + t;
    int row = s >> 3, g = s & 7;
    offA[r] = (size_t)(bm0 + row) * DD + g * 8;
    offB[r] = (size_t)(bn0 + row) * DD + g * 8;
    ldso[r] = (r * 256 + wid * 64) * 8;
  }

  f32x4 acc[4][4] = {};

  for (int kt = 0; kt < 16; ++kt) {
    int k0 = kt * 64;
    #pragma unroll
    for (int r = 0; r < 4; ++r) {
      gll16(A16 + offA[r] + k0, &lds[LDS_A + ldso[r]]);
      gll16(B16 + offB[r] + k0, &lds[LDS_B + ldso[r]]);
    }
    __syncthreads();

    #pragma unroll
    for (int kh = 0; kh < 2; ++kh) {
      f16x8 af[4], bf[4];
      #pragma unroll
      for (int i = 0; i < 4; ++i) {
        int off = (wm * 64 + i * 16 + lr) * 64 + kh * 32 + lg * 8;
        af[i] = *(const f16x8*)&lds[LDS_A + off];
      }
      #pragma unroll
      for (int j = 0; j < 4; ++j) {
        int off = (wn * 64 + j * 16 + lr) * 64 + kh * 32 + lg * 8;
        bf[j] = *(const f16x8*)&lds[LDS_B + off];
      }
      #pragma unroll
      for (int i = 0; i < 4; ++i)
        #pragma unroll
        for (int j = 0; j < 4; ++j)
          acc[i][j] = __builtin_amdgcn_mfma_f32_16x16x32_f16(af[i], bf[j], acc[i][j], 0, 0, 0);
    }
    __syncthreads();
  }

  // C/D layout: col = lane&15, row = (lane>>4)*4 + reg  [m89-verified]
  #pragma unroll
  for (int i = 0; i < 4; ++i)
    #pragma unroll
    for (int q = 0; q < 4; ++q) {
      int row = bm0 + wm * 64 + i * 16 + lg * 4 + q;
      #pragma unroll
      for (int j = 0; j < 4; ++j) {
        int col = bn0 + wn * 64 + j * 16 + lr;
        C16[(size_t)row * PP + col] = (_Float16)acc[i][j][q];
      }
    }
}

// ---------- Kernel 3: wave/row: entropy + approx top-16 + fp32 refine -------
__global__ __launch_bounds__(256) void topk_refine(const float* __restrict__ ppg,
                                                   const float* __restrict__ keys,
                                                   float* __restrict__ ws) {
  const f16* C16 = (const f16*)((const char*)ws + WS_F16_BYTE) + A16_ELEMS + B16_ELEMS;
  int wid = threadIdx.x >> 6, lane = threadIdx.x & 63;
  int row = blockIdx.x * 4 + wid;
  const f16* crow = C16 + (size_t)row * PP;

  // lane holds cols [lane*16, lane*16+16)
  f16x8 va = *(const f16x8*)(crow + lane * 16);
  f16x8 vb = *(const f16x8*)(crow + lane * 16 + 8);
  float c[16];
  #pragma unroll
  for (int j = 0; j < 8; ++j) { c[j] = (float)va[j]; c[8 + j] = (float)vb[j]; }

  // ---- entropy with fixed shift m=2 (score_ = 1-cos in [0,2]) ----
  float z = 0.f, w = 0.f;
  #pragma unroll
  for (int l = 0; l < 16; ++l) {
    float s = 1.0f - c[l];
    float e = __expf(s - 2.0f);
    z += e; w += s * e;
  }
  #pragma unroll
  for (int o = 1; o < 64; o <<= 1) { z += __shfl_xor(z, o); w += __shfl_xor(w, o); }
  if (lane == 0) ws[WS_ENT + row] = 2.0f + __logf(z) - w / z;

  // ---- approx top-16 (candidate generation) ----
  unsigned used = 0;
  int cand = 0;
  #pragma unroll
  for (int it = 0; it < 16; ++it) {
    float v = -2.0f; int gi = 1 << 30;
    #pragma unroll
    for (int l = 0; l < 16; ++l) {
      if (!((used >> l) & 1u)) {
        float cv = c[l];
        int g = lane * 16 + l;
        if (cv > v || (cv == v && g < gi)) { v = cv; gi = g; }
      }
    }
    #pragma unroll
    for (int o = 1; o < 64; o <<= 1) {
      float ov = __shfl_xor(v, o);
      int og = __shfl_xor(gi, o);
      if (ov > v || (ov == v && og < gi)) { v = ov; gi = og; }
    }
    if ((gi >> 4) == lane) used |= 1u << (gi & 15);
    if (lane == it) cand = gi;
  }

  // ---- fp32 refinement of the 16 candidates ----
  float p[16];
  const float* prow = ppg + (size_t)row * DD;
  #pragma unroll
  for (int q = 0; q < 4; ++q) {
    float4 pv = *(const float4*)(prow + lane * 16 + q * 4);
    p[q * 4 + 0] = pv.x; p[q * 4 + 1] = pv.y; p[q * 4 + 2] = pv.z; p[q * 4 + 3] = pv.w;
  }
  float ip = ws[WS_INVP + row];
  float rc[16]; int cd[16];
  #pragma unroll 4
  for (int tt = 0; tt < 16; ++tt) {
    int bc = __shfl(cand, tt);
    cd[tt] = bc;
    const float* krow = keys + (size_t)bc * DD;
    float d = 0.f;
    #pragma unroll
    for (int q = 0; q < 4; ++q) {
      float4 kv = *(const float4*)(krow + lane * 16 + q * 4);
      d = fmaf(p[q * 4 + 0], kv.x, d);
      d = fmaf(p[q * 4 + 1], kv.y, d);
      d = fmaf(p[q * 4 + 2], kv.z, d);
      d = fmaf(p[q * 4 + 3], kv.w, d);
    }
    #pragma unroll
    for (int o = 1; o < 64; o <<= 1) d += __shfl_xor(d, o);
    rc[tt] = d * ip * ws[WS_INVK + bc];
  }

  // ---- exact top-8 among refined (all lanes hold identical data) ----
  unsigned u2 = 0;
  float ssum = 0.f;
  int mysel = 0;
  #pragma unroll
  for (int it = 0; it < KSEL; ++it) {
    float bv = -2.0f; int bt = 0, bci = 1 << 30;
    #pragma unroll
    for (int tt = 0; tt < 16; ++tt) {
      if (!((u2 >> tt) & 1u)) {
        if (rc[tt] > bv || (rc[tt] == bv && cd[tt] < bci)) { bv = rc[tt]; bt = tt; bci = cd[tt]; }
      }
    }
    ssum += 1.0f - bv;
    u2 |= 1u << bt;
    if (lane == it) mysel = bci;
  }
  if (lane == 0) ws[WS_SCORE + row] = ssum;
  if (lane < KSEL) ((int*)(ws + WS_IDX))[row * KSEL + lane] = mysel;
}

// ---------- Kernel 4: gather + conv + mean + normalize + add ----------------
__global__ __launch_bounds__(256) void prompt_kernel(const float* __restrict__ ppg,
                                                     const float* __restrict__ pool,
                                                     const float* __restrict__ cw,
                                                     const float* __restrict__ cb,
                                                     const float* __restrict__ ws,
                                                     float* __restrict__ out) {
  int row = blockIdx.x;
  int t = threadIdx.x;
  const int* idx = (const int*)(ws + WS_IDX) + row * KSEL;
  float w0 = cw[0], w1 = cw[1], w2 = cw[2], bb = cb[0];
  int d0 = t * 4;

  float a0 = 0.f, a1 = 0.f, a2 = 0.f, a3 = 0.f;
  #pragma unroll
  for (int j = 0; j < KSEL; ++j) {
    int r = idx[j];
    const float* src = pool + (size_t)r * DD;
    float4 x = *(const float4*)(src + d0);
    float xm = (d0 > 0) ? src[d0 - 1] : 0.f;
    float xp = (d0 + 4 < DD) ? src[d0 + 4] : 0.f;
    float y0 = fmaf(w0, xm,  fmaf(w1, x.x, fmaf(w2, x.y, bb)));
    float y1 = fmaf(w0, x.x, fmaf(w1, x.y, fmaf(w2, x.z, bb)));
    float y2 = fmaf(w0, x.y, fmaf(w1, x.z, fmaf(w2, x.w, bb)));
    float y3 = fmaf(w0, x.z, fmaf(w1, x.w, fmaf(w2, xp, bb)));
    a0 += fmaxf(y0, 0.f);
    a1 += fmaxf(y1, 0.f);
    a2 += fmaxf(y2, 0.f);
    a3 += fmaxf(y3, 0.f);
  }
  float p0 = a0 * 0.125f, p1 = a1 * 0.125f, p2 = a2 * 0.125f, p3 = a3 * 0.125f;

  __shared__ float rmin[4], rmax[4];
  float lmin = fminf(fminf(p0, p1), fminf(p2, p3));
  float lmax = fmaxf(fmaxf(p0, p1), fmaxf(p2, p3));
  #pragma unroll
  for (int o = 32; o > 0; o >>= 1) {
    lmin = fminf(lmin, __shfl_down(lmin, o));
    lmax = fmaxf(lmax, __shfl_down(lmax, o));
  }
  if ((t & 63) == 0) { rmin[t >> 6] = lmin; rmax[t >> 6] = lmax; }
  __syncthreads();
  float pmin = fminf(fminf(rmin[0], rmin[1]), fminf(rmin[2], rmin[3]));
  float pmax = fmaxf(fmaxf(rmax[0], rmax[1]), fmaxf(rmax[2], rmax[3]));
  float scale = 2.0f / (pmax - pmin);

  float4 pv = *(const float4*)(ppg + (size_t)row * DD + d0);
  float4 o;
  o.x = pv.x + (scale * (p0 - pmin) - 1.0f);
  o.y = pv.y + (scale * (p1 - pmin) - 1.0f);
  o.z = pv.z + (scale * (p2 - pmin) - 1.0f);
  o.w = pv.w + (scale * (p3 - pmin) - 1.0f);
  *(float4*)(out + (size_t)row * DD + d0) = o;
}

// ---------- Kernel 5: deterministic final reduction -------------------------
__global__ __launch_bounds__(256) void finalize_kernel(const float* __restrict__ ws,
                                                       float* __restrict__ out) {
  int t = threadIdx.x;
  const float* ss = ws + WS_SCORE;
  const float* ee = ws + WS_ENT;
  float s = 0.f, e = 0.f;
  for (int i = t; i < BZ; i += 256) { s += ss[i]; e += ee[i]; }
  __shared__ float rs[4], re[4];
  #pragma unroll
  for (int o = 32; o > 0; o >>= 1) { s += __shfl_down(s, o); e += __shfl_down(e, o); }
  if ((t & 63) == 0) { rs[t >> 6] = s; re[t >> 6] = e; }
  __syncthreads();
  if (t == 0) {
    float sT = rs[0] + rs[1] + rs[2] + rs[3];
    float eT = re[0] + re[1] + re[2] + re[3];
    out[(size_t)BZ * DD + 0] = sT / (float)(BZ * KSEL);
    out[(size_t)BZ * DD + 1] = eT / (float)BZ;
  }
}

extern "C" void kernel_launch(void* const* d_in, const int* in_sizes, int n_in,
                              void* d_out, int out_size, void* d_ws, size_t ws_size,
                              hipStream_t stream) {
  const float* ppg  = (const float*)d_in[0];
  const float* keys = (const float*)d_in[1];
  const float* pool = (const float*)d_in[2];
  const float* cw   = (const float*)d_in[3];
  const float* cb   = (const float*)d_in[4];
  float* out = (float*)d_out;
  float* ws  = (float*)d_ws;

  hipLaunchKernelGGL(convert_f16, dim3(PP + BZ), dim3(256), 0, stream, ppg, keys, ws);
  hipLaunchKernelGGL(gemm_f16, dim3((BZ / 128) * (PP / 128)), dim3(256), 0, stream, ws, ws);
  hipLaunchKernelGGL(topk_refine, dim3(BZ / 4), dim3(256), 0, stream, ppg, keys, ws);
  hipLaunchKernelGGL(prompt_kernel, dim3(BZ), dim3(256), 0, stream, ppg, pool, cw, cb, ws, out);
  hipLaunchKernelGGL(finalize_kernel, dim3(1), dim3(256), 0, stream, ws, out);
}

// Round 5
// 175.804 us; speedup vs baseline: 1.1717x; 1.1717x over previous
//
#include <hip/hip_runtime.h>
#include <hip/hip_bf16.h>

#define BZ 8192
#define PP 1024
#define DD 1024
#define KSEL 8

typedef _Float16 f16;
typedef __attribute__((ext_vector_type(8))) _Float16 f16x8;
typedef __attribute__((ext_vector_type(4))) _Float16 f16x4;
typedef __attribute__((ext_vector_type(4))) float f32x4;
typedef __attribute__((ext_vector_type(8))) unsigned short u16x8;

// ws layout:
//   floats [0,1024)      inv-norm keys
//   floats [1024,9216)   inv-norm ppg
//   floats [9216,17408)  per-row top-8 score sum
//   floats [17408,25600) per-row entropy
//   floats [25600,91136) top-8 indices (ints)
//   byte 368640..: f16 A(8192x1024) | f16 B(1024x1024) | f16 C(8192x1024)
#define WS_INVK 0
#define WS_INVP 1024
#define WS_SCORE 9216
#define WS_ENT 17408
#define WS_IDX 25600
#define WS_F16_BYTE 368640ull
#define A16_ELEMS 8388608ull
#define B16_ELEMS 1048576ull

__device__ __forceinline__ void gll16(const void* g, void* l) {
  __builtin_amdgcn_global_load_lds((__attribute__((address_space(1))) void*)g,
                                   (__attribute__((address_space(3))) void*)l, 16, 0, 0);
}

// ---------- Kernel 1: normalize rows -> fp16, store inv norms ---------------
__global__ __launch_bounds__(256) void convert_f16(const float* __restrict__ ppg,
                                                   const float* __restrict__ keys,
                                                   float* __restrict__ ws) {
  f16* A16 = (f16*)((char*)ws + WS_F16_BYTE);
  f16* B16 = A16 + A16_ELEMS;

  int blk = blockIdx.x, t = threadIdx.x;
  const float* src; f16* dst; float* invdst;
  if (blk < PP) {
    src = keys + (size_t)blk * DD; dst = B16 + (size_t)blk * DD;
    invdst = ws + WS_INVK + blk;
  } else {
    int r = blk - PP;
    src = ppg + (size_t)r * DD; dst = A16 + (size_t)r * DD;
    invdst = ws + WS_INVP + r;
  }
  float4 v = ((const float4*)src)[t];
  float x[4] = {v.x, v.y, v.z, v.w};
  float s = x[0]*x[0] + x[1]*x[1] + x[2]*x[2] + x[3]*x[3];
  __shared__ float red[4];
  #pragma unroll
  for (int o = 32; o > 0; o >>= 1) s += __shfl_down(s, o);
  if ((t & 63) == 0) red[t >> 6] = s;
  __syncthreads();
  float tot = red[0] + red[1] + red[2] + red[3];
  float inv = 1.0f / fmaxf(sqrtf(tot), 1e-8f);
  f16x4 h;
  #pragma unroll
  for (int j = 0; j < 4; ++j) h[j] = (_Float16)(x[j] * inv);
  *(f16x4*)(dst + t * 4) = h;
  if (t == 0) *invdst = inv;
}

// ---------- Kernel 2: single-pass fp16 MFMA GEMM -> approx cos (f16) --------
#define LDS_A 0
#define LDS_B 8192

__global__ __launch_bounds__(256, 2) void gemm_f16(const float* __restrict__ ws_ro,
                                                   float* __restrict__ ws_w) {
  const f16* A16 = (const f16*)((const char*)ws_ro + WS_F16_BYTE);
  const f16* B16 = A16 + A16_ELEMS;
  f16* C16 = (f16*)((char*)ws_w + WS_F16_BYTE) + A16_ELEMS + B16_ELEMS;

  __shared__ unsigned short lds[16384];  // 32 KB: A 128x64 f16 | B 128x64 f16

  int t = threadIdx.x;
  int wid = t >> 6, lane = t & 63;
  int lr = lane & 15, lg = lane >> 4;

  int orig = blockIdx.x;
  int wg = (orig & 7) * 64 + (orig >> 3);
  int bm0 = (wg >> 3) * 128;
  int bn0 = (wg & 7) * 128;
  int wm = wid >> 1, wn = wid & 1;

  size_t offA[4], offB[4];
  int ldso[4];
  #pragma unroll
  for (int r = 0; r < 4; ++r) {
    int s = r * 256 + t;
    int row = s >> 3, g = s & 7;
    offA[r] = (size_t)(bm0 + row) * DD + g * 8;
    offB[r] = (size_t)(bn0 + row) * DD + g * 8;
    ldso[r] = (r * 256 + wid * 64) * 8;
  }

  f32x4 acc[4][4] = {};

  for (int kt = 0; kt < 16; ++kt) {
    int k0 = kt * 64;
    #pragma unroll
    for (int r = 0; r < 4; ++r) {
      gll16(A16 + offA[r] + k0, &lds[LDS_A + ldso[r]]);
      gll16(B16 + offB[r] + k0, &lds[LDS_B + ldso[r]]);
    }
    __syncthreads();

    #pragma unroll
    for (int kh = 0; kh < 2; ++kh) {
      f16x8 af[4], bf[4];
      #pragma unroll
      for (int i = 0; i < 4; ++i) {
        int off = (wm * 64 + i * 16 + lr) * 64 + kh * 32 + lg * 8;
        af[i] = *(const f16x8*)&lds[LDS_A + off];
      }
      #pragma unroll
      for (int j = 0; j < 4; ++j) {
        int off = (wn * 64 + j * 16 + lr) * 64 + kh * 32 + lg * 8;
        bf[j] = *(const f16x8*)&lds[LDS_B + off];
      }
      #pragma unroll
      for (int i = 0; i < 4; ++i)
        #pragma unroll
        for (int j = 0; j < 4; ++j)
          acc[i][j] = __builtin_amdgcn_mfma_f32_16x16x32_f16(af[i], bf[j], acc[i][j], 0, 0, 0);
    }
    __syncthreads();
  }

  #pragma unroll
  for (int i = 0; i < 4; ++i)
    #pragma unroll
    for (int q = 0; q < 4; ++q) {
      int row = bm0 + wm * 64 + i * 16 + lg * 4 + q;
      #pragma unroll
      for (int j = 0; j < 4; ++j) {
        int col = bn0 + wn * 64 + j * 16 + lr;
        C16[(size_t)row * PP + col] = (_Float16)acc[i][j][q];
      }
    }
}

// ---------- Kernel 3: packed-key top-16 + distributed fp32 refine -----------
__global__ __launch_bounds__(256) void topk_refine(const float* __restrict__ ppg,
                                                   const float* __restrict__ keys,
                                                   float* __restrict__ ws) {
  const unsigned short* C16 =
      (const unsigned short*)((const char*)ws + WS_F16_BYTE) + A16_ELEMS + B16_ELEMS;
  int wid = threadIdx.x >> 6, lane = threadIdx.x & 63;
  int row = blockIdx.x * 4 + wid;
  const unsigned short* crow = C16 + (size_t)row * PP;

  // lane holds cols [lane*16, lane*16+16) as raw fp16 bits
  u16x8 va = *(const u16x8*)(crow + lane * 16);
  u16x8 vb = *(const u16x8*)(crow + lane * 16 + 8);

  // ---- entropy with fixed shift m=2 (score_ = 1-cos in [0,2]) ----
  {
    float z = 0.f, w = 0.f;
    #pragma unroll
    for (int l = 0; l < 16; ++l) {
      unsigned short b = (l < 8) ? (unsigned short)va[l] : (unsigned short)vb[l - 8];
      float cval = (float)__builtin_bit_cast(f16, b);
      float s = 1.0f - cval;
      float e = __expf(s - 2.0f);
      z += e; w += s * e;
    }
    #pragma unroll
    for (int o = 1; o < 64; o <<= 1) { z += __shfl_xor(z, o); w += __shfl_xor(w, o); }
    if (lane == 0) ws[WS_ENT + row] = 2.0f + __logf(z) - w / z;
  }

  // ---- packed sortable keys: (mono16(cos) << 16) | (1023 - gidx) ----
  unsigned key[16];
  #pragma unroll
  for (int l = 0; l < 16; ++l) {
    unsigned b = (l < 8) ? (unsigned)(unsigned short)va[l] : (unsigned)(unsigned short)vb[l - 8];
    unsigned m16 = b ^ ((b >> 15) * 0x7FFFu) ^ 0x8000u;  // monotone fp16 order
    key[l] = (m16 << 16) | (unsigned)(1023 - (lane * 16 + l));
  }

  // ---- approx top-16 via 16 rounds of wave-max on u32 keys ----
  unsigned win = 0;
  #pragma unroll
  for (int it = 0; it < 16; ++it) {
    unsigned m = key[0];
    #pragma unroll
    for (int l = 1; l < 16; ++l) m = (key[l] > m) ? key[l] : m;
    #pragma unroll
    for (int o = 1; o < 64; o <<= 1) {
      unsigned om = __shfl_xor(m, o);
      m = (om > m) ? om : m;
    }
    if (lane == it) win = m;
    #pragma unroll
    for (int l = 0; l < 16; ++l) key[l] = (key[l] == m) ? 0u : key[l];
  }

  // ---- distributed fp32 refine: candidate = lane&15, segment = lane>>4 ----
  unsigned wk = __shfl(win, lane & 15);
  int cidx = 1023 - (int)(wk & 1023u);
  int seg = lane >> 4;
  const float* kp = keys + (size_t)cidx * DD + seg * 256;
  const float* pp = ppg + (size_t)row * DD + seg * 256;
  float d0 = 0.f, d1 = 0.f;
  #pragma unroll 8
  for (int ch = 0; ch < 64; ++ch) {
    float4 kv = ((const float4*)kp)[ch];
    float4 pv = ((const float4*)pp)[ch];
    d0 = fmaf(kv.x, pv.x, d0);
    d1 = fmaf(kv.y, pv.y, d1);
    d0 = fmaf(kv.z, pv.z, d0);
    d1 = fmaf(kv.w, pv.w, d1);
  }
  float d = d0 + d1;
  d += __shfl_xor(d, 16);
  d += __shfl_xor(d, 32);
  float rc = d * ws[WS_INVP + row] * ws[WS_INVK + cidx];

  // ---- exact top-8: 16-lane bitonic sort descending on (mono32(rc), idx) ----
  unsigned fb = __builtin_bit_cast(unsigned, rc);
  unsigned mv = fb ^ ((unsigned)((int)fb >> 31) | 0x80000000u);
  unsigned long long skey = ((unsigned long long)mv << 10) | (unsigned)(1023 - cidx);

  #pragma unroll
  for (unsigned k = 2; k <= 16; k <<= 1) {
    #pragma unroll
    for (unsigned j = k >> 1; j > 0; j >>= 1) {
      unsigned long long p = __shfl_xor(skey, (int)j);
      bool takeMax = (((unsigned)lane & j) == 0) ^ (((unsigned)lane & k) != 0);
      skey = takeMax ? (skey > p ? skey : p) : (skey < p ? skey : p);
    }
  }
  // group 0 (lanes 0-15) sorted descending: lane i = i-th largest refined cos
  unsigned mv2 = (unsigned)(skey >> 10);
  unsigned fb2 = mv2 ^ ((mv2 & 0x80000000u) ? 0x80000000u : 0xFFFFFFFFu);
  float val = __builtin_bit_cast(float, fb2);
  int ci = 1023 - (int)(skey & 1023u);

  float ssum = ((lane & 15) < 8) ? (1.0f - val) : 0.f;
  #pragma unroll
  for (int o = 1; o < 16; o <<= 1) ssum += __shfl_xor(ssum, o);
  if (lane == 0) ws[WS_SCORE + row] = ssum;
  if (lane < KSEL) ((int*)(ws + WS_IDX))[row * KSEL + lane] = ci;
}

// ---------- Kernel 4: gather + conv + mean + normalize + add ----------------
__global__ __launch_bounds__(256) void prompt_kernel(const float* __restrict__ ppg,
                                                     const float* __restrict__ pool,
                                                     const float* __restrict__ cw,
                                                     const float* __restrict__ cb,
                                                     const float* __restrict__ ws,
                                                     float* __restrict__ out) {
  int row = blockIdx.x;
  int t = threadIdx.x;
  const int* idx = (const int*)(ws + WS_IDX) + row * KSEL;
  float w0 = cw[0], w1 = cw[1], w2 = cw[2], bb = cb[0];
  int d0 = t * 4;

  float a0 = 0.f, a1 = 0.f, a2 = 0.f, a3 = 0.f;
  #pragma unroll
  for (int j = 0; j < KSEL; ++j) {
    int r = idx[j];
    const float* src = pool + (size_t)r * DD;
    float4 x = *(const float4*)(src + d0);
    float xm = (d0 > 0) ? src[d0 - 1] : 0.f;
    float xp = (d0 + 4 < DD) ? src[d0 + 4] : 0.f;
    float y0 = fmaf(w0, xm,  fmaf(w1, x.x, fmaf(w2, x.y, bb)));
    float y1 = fmaf(w0, x.x, fmaf(w1, x.y, fmaf(w2, x.z, bb)));
    float y2 = fmaf(w0, x.y, fmaf(w1, x.z, fmaf(w2, x.w, bb)));
    float y3 = fmaf(w0, x.z, fmaf(w1, x.w, fmaf(w2, xp, bb)));
    a0 += fmaxf(y0, 0.f);
    a1 += fmaxf(y1, 0.f);
    a2 += fmaxf(y2, 0.f);
    a3 += fmaxf(y3, 0.f);
  }
  float p0 = a0 * 0.125f, p1 = a1 * 0.125f, p2 = a2 * 0.125f, p3 = a3 * 0.125f;

  __shared__ float rmin[4], rmax[4];
  float lmin = fminf(fminf(p0, p1), fminf(p2, p3));
  float lmax = fmaxf(fmaxf(p0, p1), fmaxf(p2, p3));
  #pragma unroll
  for (int o = 32; o > 0; o >>= 1) {
    lmin = fminf(lmin, __shfl_down(lmin, o));
    lmax = fmaxf(lmax, __shfl_down(lmax, o));
  }
  if ((t & 63) == 0) { rmin[t >> 6] = lmin; rmax[t >> 6] = lmax; }
  __syncthreads();
  float pmin = fminf(fminf(rmin[0], rmin[1]), fminf(rmin[2], rmin[3]));
  float pmax = fmaxf(fmaxf(rmax[0], rmax[1]), fmaxf(rmax[2], rmax[3]));
  float scale = 2.0f / (pmax - pmin);

  float4 pv = *(const float4*)(ppg + (size_t)row * DD + d0);
  float4 o;
  o.x = pv.x + (scale * (p0 - pmin) - 1.0f);
  o.y = pv.y + (scale * (p1 - pmin) - 1.0f);
  o.z = pv.z + (scale * (p2 - pmin) - 1.0f);
  o.w = pv.w + (scale * (p3 - pmin) - 1.0f);
  *(float4*)(out + (size_t)row * DD + d0) = o;
}

// ---------- Kernel 5: deterministic final reduction -------------------------
__global__ __launch_bounds__(256) void finalize_kernel(const float* __restrict__ ws,
                                                       float* __restrict__ out) {
  int t = threadIdx.x;
  const float* ss = ws + WS_SCORE;
  const float* ee = ws + WS_ENT;
  float s = 0.f, e = 0.f;
  for (int i = t; i < BZ; i += 256) { s += ss[i]; e += ee[i]; }
  __shared__ float rs[4], re[4];
  #pragma unroll
  for (int o = 32; o > 0; o >>= 1) { s += __shfl_down(s, o); e += __shfl_down(e, o); }
  if ((t & 63) == 0) { rs[t >> 6] = s; re[t >> 6] = e; }
  __syncthreads();
  if (t == 0) {
    float sT = rs[0] + rs[1] + rs[2] + rs[3];
    float eT = re[0] + re[1] + re[2] + re[3];
    out[(size_t)BZ * DD + 0] = sT / (float)(BZ * KSEL);
    out[(size_t)BZ * DD + 1] = eT / (float)BZ;
  }
}

extern "C" void kernel_launch(void* const* d_in, const int* in_sizes, int n_in,
                              void* d_out, int out_size, void* d_ws, size_t ws_size,
                              hipStream_t stream) {
  const float* ppg  = (const float*)d_in[0];
  const float* keys = (const float*)d_in[1];
  const float* pool = (const float*)d_in[2];
  const float* cw   = (const float*)d_in[3];
  const float* cb   = (const float*)d_in[4];
  float* out = (float*)d_out;
  float* ws  = (float*)d_ws;

  hipLaunchKernelGGL(convert_f16, dim3(PP + BZ), dim3(256), 0, stream, ppg, keys, ws);
  hipLaunchKernelGGL(gemm_f16, dim3((BZ / 128) * (PP / 128)), dim3(256), 0, stream, ws, ws);
  hipLaunchKernelGGL(topk_refine, dim3(BZ / 4), dim3(256), 0, stream, ppg, keys, ws);
  hipLaunchKernelGGL(prompt_kernel, dim3(BZ), dim3(256), 0, stream, ppg, pool, cw, cb, ws, out);
  hipLaunchKernelGGL(finalize_kernel, dim3(1), dim3(256), 0, stream, ws, out);
}

// Round 6
// 155.064 us; speedup vs baseline: 1.3284x; 1.1338x over previous
//
#include <hip/hip_runtime.h>
#include <hip/hip_bf16.h>

#define BZ 8192
#define PP 1024
#define DD 1024
#define KSEL 8

typedef _Float16 f16;
typedef __attribute__((ext_vector_type(8))) _Float16 f16x8;
typedef __attribute__((ext_vector_type(4))) _Float16 f16x4;
typedef __attribute__((ext_vector_type(4))) float f32x4;
typedef __attribute__((ext_vector_type(8))) unsigned short u16x8;

// ws layout:
//   floats [0,1024)      inv-norm keys
//   floats [1024,9216)   inv-norm ppg
//   floats [9216,17408)  per-row top-8 score sum
//   floats [17408,25600) per-row entropy
//   byte 368640..: f16 A(8192x1024) | f16 B(1024x1024) | f16 C(8192x1024)
#define WS_INVK 0
#define WS_INVP 1024
#define WS_SCORE 9216
#define WS_ENT 17408
#define WS_F16_BYTE 368640ull
#define A16_ELEMS 8388608ull
#define B16_ELEMS 1048576ull

__device__ __forceinline__ void gll16(const void* g, void* l) {
  __builtin_amdgcn_global_load_lds((__attribute__((address_space(1))) void*)g,
                                   (__attribute__((address_space(3))) void*)l, 16, 0, 0);
}

// ---------- Kernel 1: normalize rows -> fp16, store inv norms ---------------
__global__ __launch_bounds__(256) void convert_f16(const float* __restrict__ ppg,
                                                   const float* __restrict__ keys,
                                                   float* __restrict__ ws) {
  f16* A16 = (f16*)((char*)ws + WS_F16_BYTE);
  f16* B16 = A16 + A16_ELEMS;

  int blk = blockIdx.x, t = threadIdx.x;
  const float* src; f16* dst; float* invdst;
  if (blk < PP) {
    src = keys + (size_t)blk * DD; dst = B16 + (size_t)blk * DD;
    invdst = ws + WS_INVK + blk;
  } else {
    int r = blk - PP;
    src = ppg + (size_t)r * DD; dst = A16 + (size_t)r * DD;
    invdst = ws + WS_INVP + r;
  }
  float4 v = ((const float4*)src)[t];
  float x[4] = {v.x, v.y, v.z, v.w};
  float s = x[0]*x[0] + x[1]*x[1] + x[2]*x[2] + x[3]*x[3];
  __shared__ float red[4];
  #pragma unroll
  for (int o = 32; o > 0; o >>= 1) s += __shfl_down(s, o);
  if ((t & 63) == 0) red[t >> 6] = s;
  __syncthreads();
  float tot = red[0] + red[1] + red[2] + red[3];
  float inv = 1.0f / fmaxf(sqrtf(tot), 1e-8f);
  f16x4 h;
  #pragma unroll
  for (int j = 0; j < 4; ++j) h[j] = (_Float16)(x[j] * inv);
  *(f16x4*)(dst + t * 4) = h;
  if (t == 0) *invdst = inv;
}

// ---------- Kernel 2: single-pass fp16 MFMA GEMM -> approx cos (f16) --------
#define LDS_A 0
#define LDS_B 8192

__global__ __launch_bounds__(256, 2) void gemm_f16(const float* __restrict__ ws_ro,
                                                   float* __restrict__ ws_w) {
  const f16* A16 = (const f16*)((const char*)ws_ro + WS_F16_BYTE);
  const f16* B16 = A16 + A16_ELEMS;
  f16* C16 = (f16*)((char*)ws_w + WS_F16_BYTE) + A16_ELEMS + B16_ELEMS;

  __shared__ unsigned short lds[16384];  // 32 KB: A 128x64 f16 | B 128x64 f16

  int t = threadIdx.x;
  int wid = t >> 6, lane = t & 63;
  int lr = lane & 15, lg = lane >> 4;

  int orig = blockIdx.x;
  int wg = (orig & 7) * 64 + (orig >> 3);
  int bm0 = (wg >> 3) * 128;
  int bn0 = (wg & 7) * 128;
  int wm = wid >> 1, wn = wid & 1;

  size_t offA[4], offB[4];
  int ldso[4];
  #pragma unroll
  for (int r = 0; r < 4; ++r) {
    int s = r * 256 + t;
    int row = s >> 3, g = s & 7;
    offA[r] = (size_t)(bm0 + row) * DD + g * 8;
    offB[r] = (size_t)(bn0 + row) * DD + g * 8;
    ldso[r] = (r * 256 + wid * 64) * 8;
  }

  f32x4 acc[4][4] = {};

  for (int kt = 0; kt < 16; ++kt) {
    int k0 = kt * 64;
    #pragma unroll
    for (int r = 0; r < 4; ++r) {
      gll16(A16 + offA[r] + k0, &lds[LDS_A + ldso[r]]);
      gll16(B16 + offB[r] + k0, &lds[LDS_B + ldso[r]]);
    }
    __syncthreads();

    #pragma unroll
    for (int kh = 0; kh < 2; ++kh) {
      f16x8 af[4], bf[4];
      #pragma unroll
      for (int i = 0; i < 4; ++i) {
        int off = (wm * 64 + i * 16 + lr) * 64 + kh * 32 + lg * 8;
        af[i] = *(const f16x8*)&lds[LDS_A + off];
      }
      #pragma unroll
      for (int j = 0; j < 4; ++j) {
        int off = (wn * 64 + j * 16 + lr) * 64 + kh * 32 + lg * 8;
        bf[j] = *(const f16x8*)&lds[LDS_B + off];
      }
      #pragma unroll
      for (int i = 0; i < 4; ++i)
        #pragma unroll
        for (int j = 0; j < 4; ++j)
          acc[i][j] = __builtin_amdgcn_mfma_f32_16x16x32_f16(af[i], bf[j], acc[i][j], 0, 0, 0);
    }
    __syncthreads();
  }

  #pragma unroll
  for (int i = 0; i < 4; ++i)
    #pragma unroll
    for (int q = 0; q < 4; ++q) {
      int row = bm0 + wm * 64 + i * 16 + lg * 4 + q;
      #pragma unroll
      for (int j = 0; j < 4; ++j) {
        int col = bn0 + wn * 64 + j * 16 + lr;
        C16[(size_t)row * PP + col] = (_Float16)acc[i][j][q];
      }
    }
}

// ---------- Kernel 3: fused entropy + top-16 + coalesced refine + prompt ----
// One wave per batch-row. 4 waves/block, no LDS, no block barriers.
__global__ __launch_bounds__(256) void fused_topk_prompt(const float* __restrict__ ppg,
                                                         const float* __restrict__ keys,
                                                         const float* __restrict__ pool,
                                                         const float* __restrict__ cw,
                                                         const float* __restrict__ cb,
                                                         float* __restrict__ ws,
                                                         float* __restrict__ out) {
  const unsigned short* C16 =
      (const unsigned short*)((const char*)ws + WS_F16_BYTE) + A16_ELEMS + B16_ELEMS;
  int wid = threadIdx.x >> 6, lane = threadIdx.x & 63;
  int row = blockIdx.x * 4 + wid;
  const unsigned short* crow = C16 + (size_t)row * PP;

  // lane holds cols [lane*16, lane*16+16) as raw fp16 bits
  u16x8 va = *(const u16x8*)(crow + lane * 16);
  u16x8 vb = *(const u16x8*)(crow + lane * 16 + 8);

  // ---- entropy with fixed shift m=2 (score_ = 1-cos in [0,2]) ----
  {
    float z = 0.f, w = 0.f;
    #pragma unroll
    for (int l = 0; l < 16; ++l) {
      unsigned short b = (l < 8) ? (unsigned short)va[l] : (unsigned short)vb[l - 8];
      float cval = (float)__builtin_bit_cast(f16, b);
      float s = 1.0f - cval;
      float e = __expf(s - 2.0f);
      z += e; w += s * e;
    }
    #pragma unroll
    for (int o = 1; o < 64; o <<= 1) { z += __shfl_xor(z, o); w += __shfl_xor(w, o); }
    if (lane == 0) ws[WS_ENT + row] = 2.0f + __logf(z) - w / z;
  }

  // ---- packed sortable keys: (mono16(cos) << 16) | (1023 - gidx) ----
  unsigned key[16];
  #pragma unroll
  for (int l = 0; l < 16; ++l) {
    unsigned b = (l < 8) ? (unsigned)(unsigned short)va[l] : (unsigned)(unsigned short)vb[l - 8];
    unsigned m16 = b ^ ((b >> 15) * 0x7FFFu) ^ 0x8000u;
    key[l] = (m16 << 16) | (unsigned)(1023 - (lane * 16 + l));
  }

  // ---- approx top-16 via 16 rounds of wave-max on u32 keys ----
  unsigned win = 0;
  #pragma unroll
  for (int it = 0; it < 16; ++it) {
    unsigned m = key[0];
    #pragma unroll
    for (int l = 1; l < 16; ++l) m = (key[l] > m) ? key[l] : m;
    #pragma unroll
    for (int o = 1; o < 64; o <<= 1) {
      unsigned om = __shfl_xor(m, o);
      m = (om > m) ? om : m;
    }
    if (lane == it) win = m;
    #pragma unroll
    for (int l = 0; l < 16; ++l) key[l] = (key[l] == m) ? 0u : key[l];
  }

  // ---- ppg row once into regs, chunk layout: pv[j] = elems j*256 + lane*4 ----
  const float* prow = ppg + (size_t)row * DD;
  f32x4 pv[4];
  #pragma unroll
  for (int j = 0; j < 4; ++j)
    pv[j] = *(const f32x4*)(prow + j * 256 + lane * 4);
  float ip = ws[WS_INVP + row];

  // ---- coalesced fp32 refine: whole wave per candidate, 16 candidates ----
  float myrc = 0.f; int myci = 0;
  #pragma unroll
  for (int t = 0; t < 16; ++t) {
    int ct = 1023 - (int)(__shfl(win, t) & 1023u);
    const float* krow = keys + (size_t)ct * DD;
    float d = 0.f;
    #pragma unroll
    for (int j = 0; j < 4; ++j) {
      f32x4 kv = *(const f32x4*)(krow + j * 256 + lane * 4);
      d = fmaf(kv[0], pv[j][0], d);
      d = fmaf(kv[1], pv[j][1], d);
      d = fmaf(kv[2], pv[j][2], d);
      d = fmaf(kv[3], pv[j][3], d);
    }
    #pragma unroll
    for (int o = 1; o < 64; o <<= 1) d += __shfl_xor(d, o);
    float rcv = d * ip * ws[WS_INVK + ct];
    if ((lane & 15) == t) { myrc = rcv; myci = ct; }
  }

  // ---- exact top-8: 16-lane bitonic sort descending on (mono32, idx) ----
  unsigned fb = __builtin_bit_cast(unsigned, myrc);
  unsigned mv = fb ^ ((unsigned)((int)fb >> 31) | 0x80000000u);
  unsigned long long skey = ((unsigned long long)mv << 10) | (unsigned)(1023 - myci);
  #pragma unroll
  for (unsigned k = 2; k <= 16; k <<= 1) {
    #pragma unroll
    for (unsigned j = k >> 1; j > 0; j >>= 1) {
      unsigned long long p = __shfl_xor(skey, (int)j);
      bool takeMax = (((unsigned)lane & j) == 0) ^ (((unsigned)lane & k) != 0);
      skey = takeMax ? (skey > p ? skey : p) : (skey < p ? skey : p);
    }
  }
  {
    unsigned mv2 = (unsigned)(skey >> 10);
    unsigned fb2 = mv2 ^ ((mv2 & 0x80000000u) ? 0x80000000u : 0xFFFFFFFFu);
    float val = __builtin_bit_cast(float, fb2);
    float ssum = ((lane & 15) < 8) ? (1.0f - val) : 0.f;
    #pragma unroll
    for (int o = 1; o < 16; o <<= 1) ssum += __shfl_xor(ssum, o);
    if (lane == 0) ws[WS_SCORE + row] = ssum;
  }

  // ---- prompt: gather 8 pool rows (wave-coalesced), conv, mean ----
  float w0 = cw[0], w1 = cw[1], w2 = cw[2], bb = cb[0];
  float a[16] = {};
  #pragma unroll
  for (int s = 0; s < 8; ++s) {
    int rj = 1023 - (int)(__shfl(skey, s) & 1023u);
    const float* src = pool + (size_t)rj * DD;
    #pragma unroll
    for (int j = 0; j < 4; ++j) {
      int d0 = j * 256 + lane * 4;
      f32x4 x = *(const f32x4*)(src + d0);
      float xm = (d0 > 0) ? src[d0 - 1] : 0.f;
      float xp = (d0 + 4 < DD) ? src[d0 + 4] : 0.f;
      float y0 = fmaf(w0, xm,   fmaf(w1, x[0], fmaf(w2, x[1], bb)));
      float y1 = fmaf(w0, x[0], fmaf(w1, x[1], fmaf(w2, x[2], bb)));
      float y2 = fmaf(w0, x[1], fmaf(w1, x[2], fmaf(w2, x[3], bb)));
      float y3 = fmaf(w0, x[2], fmaf(w1, x[3], fmaf(w2, xp,   bb)));
      a[j * 4 + 0] += fmaxf(y0, 0.f);
      a[j * 4 + 1] += fmaxf(y1, 0.f);
      a[j * 4 + 2] += fmaxf(y2, 0.f);
      a[j * 4 + 3] += fmaxf(y3, 0.f);
    }
  }
  #pragma unroll
  for (int l = 0; l < 16; ++l) a[l] *= 0.125f;

  // ---- wave min/max over the 1024 prompt values ----
  float lmin = a[0], lmax = a[0];
  #pragma unroll
  for (int l = 1; l < 16; ++l) { lmin = fminf(lmin, a[l]); lmax = fmaxf(lmax, a[l]); }
  #pragma unroll
  for (int o = 1; o < 64; o <<= 1) {
    lmin = fminf(lmin, __shfl_xor(lmin, o));
    lmax = fmaxf(lmax, __shfl_xor(lmax, o));
  }
  float scale = 2.0f / (lmax - lmin);

  // ---- normalize + add ppg (still in regs) + write ----
  float* orow = out + (size_t)row * DD;
  #pragma unroll
  for (int j = 0; j < 4; ++j) {
    f32x4 o4;
    #pragma unroll
    for (int q = 0; q < 4; ++q)
      o4[q] = pv[j][q] + (scale * (a[j * 4 + q] - lmin) - 1.0f);
    *(f32x4*)(orow + j * 256 + lane * 4) = o4;
  }
}

// ---------- Kernel 4: deterministic final reduction -------------------------
__global__ __launch_bounds__(256) void finalize_kernel(const float* __restrict__ ws,
                                                       float* __restrict__ out) {
  int t = threadIdx.x;
  const float* ss = ws + WS_SCORE;
  const float* ee = ws + WS_ENT;
  float s = 0.f, e = 0.f;
  for (int i = t; i < BZ; i += 256) { s += ss[i]; e += ee[i]; }
  __shared__ float rs[4], re[4];
  #pragma unroll
  for (int o = 32; o > 0; o >>= 1) { s += __shfl_down(s, o); e += __shfl_down(e, o); }
  if ((t & 63) == 0) { rs[t >> 6] = s; re[t >> 6] = e; }
  __syncthreads();
  if (t == 0) {
    float sT = rs[0] + rs[1] + rs[2] + rs[3];
    float eT = re[0] + re[1] + re[2] + re[3];
    out[(size_t)BZ * DD + 0] = sT / (float)(BZ * KSEL);
    out[(size_t)BZ * DD + 1] = eT / (float)BZ;
  }
}

extern "C" void kernel_launch(void* const* d_in, const int* in_sizes, int n_in,
                              void* d_out, int out_size, void* d_ws, size_t ws_size,
                              hipStream_t stream) {
  const float* ppg  = (const float*)d_in[0];
  const float* keys = (const float*)d_in[1];
  const float* pool = (const float*)d_in[2];
  const float* cw   = (const float*)d_in[3];
  const float* cb   = (const float*)d_in[4];
  float* out = (float*)d_out;
  float* ws  = (float*)d_ws;

  hipLaunchKernelGGL(convert_f16, dim3(PP + BZ), dim3(256), 0, stream, ppg, keys, ws);
  hipLaunchKernelGGL(gemm_f16, dim3((BZ / 128) * (PP / 128)), dim3(256), 0, stream, ws, ws);
  hipLaunchKernelGGL(fused_topk_prompt, dim3(BZ / 4), dim3(256), 0, stream,
                     ppg, keys, pool, cw, cb, ws, out);
  hipLaunchKernelGGL(finalize_kernel, dim3(1), dim3(256), 0, stream, ws, out);
}

// Round 8
// 153.416 us; speedup vs baseline: 1.3427x; 1.0107x over previous
//
#include <hip/hip_runtime.h>
#include <hip/hip_bf16.h>

#define BZ 8192
#define PP 1024
#define DD 1024
#define KSEL 8

typedef unsigned short u16;
typedef __attribute__((ext_vector_type(8))) short bf16x8;
typedef __attribute__((ext_vector_type(4))) float f32x4;

// ws layout (floats):
//   [0,1024)       inv-norm keys
//   [1024,9216)    inv-norm ppg
//   [9216,17408)   per-row top-8 score sum
//   [17408,25600)  per-row entropy
//   byte 368640 .. : bf16 A_hi, A_lo (16MB each), B_hi, B_lo (2MB each)
// C (fp32 cos matrix) lives in d_out; fused kernel reads row then overwrites.
#define WS_INVK 0
#define WS_INVP 1024
#define WS_SCORE 9216
#define WS_ENT 17408
#define WS_BF16_BYTE 368640ull

__device__ __forceinline__ u16 f2bf(float x) {
  __hip_bfloat16 h = __float2bfloat16(x);
  return *(u16*)&h;
}
__device__ __forceinline__ float bf2f(u16 u) {
  __hip_bfloat16 h; *(u16*)&h = u;
  return __bfloat162float(h);
}
__device__ __forceinline__ void gll16(const void* g, void* l) {
  __builtin_amdgcn_global_load_lds((__attribute__((address_space(1))) void*)g,
                                   (__attribute__((address_space(3))) void*)l, 16, 0, 0);
}

// ---------- Kernel 1: fused fp32->bf16 hi/lo conversion + inverse norms ------
// (verbatim from round 3 — validated)
__global__ __launch_bounds__(256) void convert_kernel(const float* __restrict__ ppg,
                                                      const float* __restrict__ keys,
                                                      float* __restrict__ ws) {
  u16* Ahi = (u16*)((char*)ws + WS_BF16_BYTE);
  u16* Alo = Ahi + 8388608;
  u16* Bhi = Alo + 8388608;
  u16* Blo = Bhi + 1048576;

  int blk = blockIdx.x;
  const float* src; u16 *hi, *lo; float* invdst;
  if (blk < PP) {
    src = keys + (size_t)blk * DD;
    hi = Bhi + (size_t)blk * DD; lo = Blo + (size_t)blk * DD;
    invdst = ws + WS_INVK + blk;
  } else {
    int r = blk - PP;
    src = ppg + (size_t)r * DD;
    hi = Ahi + (size_t)r * DD; lo = Alo + (size_t)r * DD;
    invdst = ws + WS_INVP + r;
  }
  int t = threadIdx.x;
  float4 v = ((const float4*)src)[t];
  float x[4] = {v.x, v.y, v.z, v.w};
  u16 h4[4], l4[4];
  float s = 0.f;
  #pragma unroll
  for (int j = 0; j < 4; ++j) {
    h4[j] = f2bf(x[j]);
    l4[j] = f2bf(x[j] - bf2f(h4[j]));
    s += x[j] * x[j];
  }
  *(ushort4*)(hi + t * 4) = *(ushort4*)h4;
  *(ushort4*)(lo + t * 4) = *(ushort4*)l4;

  __shared__ float red[4];
  #pragma unroll
  for (int o = 32; o > 0; o >>= 1) s += __shfl_down(s, o);
  if ((t & 63) == 0) red[t >> 6] = s;
  __syncthreads();
  if (t == 0) {
    float tot = red[0] + red[1] + red[2] + red[3];
    *invdst = 1.0f / fmaxf(sqrtf(tot), 1e-8f);
  }
}

// ---------- Kernel 2: 3-pass bf16 hi/lo MFMA GEMM -> fp32 cos in d_out ------
// (verbatim from round 3 — validated)
#define LDS_AH 0
#define LDS_AL 8192
#define LDS_BH 16384
#define LDS_BL 24576

__global__ __launch_bounds__(256, 2) void gemm_mfma(const float* __restrict__ ws_ro,
                                                    float* __restrict__ C) {
  const u16* Ahi = (const u16*)((const char*)ws_ro + WS_BF16_BYTE);
  const u16* Alo = Ahi + 8388608;
  const u16* Bhi = Alo + 8388608;
  const u16* Blo = Bhi + 1048576;

  __shared__ u16 lds[32768];  // 64 KB

  int t = threadIdx.x;
  int wid = t >> 6, lane = t & 63;
  int lr = lane & 15, lg = lane >> 4;

  int orig = blockIdx.x;
  int wg = (orig & 7) * 64 + (orig >> 3);
  int bm0 = (wg >> 3) * 128;
  int bn0 = (wg & 7) * 128;
  int wm = wid >> 1, wn = wid & 1;

  size_t offA[4], offB[4];
  int ldso[4];
  #pragma unroll
  for (int r = 0; r < 4; ++r) {
    int s = r * 256 + t;
    int row = s >> 3, g = s & 7;
    offA[r] = (size_t)(bm0 + row) * DD + g * 8;
    offB[r] = (size_t)(bn0 + row) * DD + g * 8;
    ldso[r] = (r * 256 + wid * 64) * 8;
  }

  f32x4 acc[4][4] = {};

  for (int kt = 0; kt < 16; ++kt) {
    int k0 = kt * 64;
    #pragma unroll
    for (int r = 0; r < 4; ++r) {
      gll16(Ahi + offA[r] + k0, &lds[LDS_AH + ldso[r]]);
      gll16(Alo + offA[r] + k0, &lds[LDS_AL + ldso[r]]);
      gll16(Bhi + offB[r] + k0, &lds[LDS_BH + ldso[r]]);
      gll16(Blo + offB[r] + k0, &lds[LDS_BL + ldso[r]]);
    }
    __syncthreads();

    #pragma unroll
    for (int kh = 0; kh < 2; ++kh) {
      bf16x8 ah[4], al[4], bh[4], bl[4];
      #pragma unroll
      for (int i = 0; i < 4; ++i) {
        int off = (wm * 64 + i * 16 + lr) * 64 + kh * 32 + lg * 8;
        ah[i] = *(const bf16x8*)&lds[LDS_AH + off];
        al[i] = *(const bf16x8*)&lds[LDS_AL + off];
      }
      #pragma unroll
      for (int j = 0; j < 4; ++j) {
        int off = (wn * 64 + j * 16 + lr) * 64 + kh * 32 + lg * 8;
        bh[j] = *(const bf16x8*)&lds[LDS_BH + off];
        bl[j] = *(const bf16x8*)&lds[LDS_BL + off];
      }
      #pragma unroll
      for (int i = 0; i < 4; ++i)
        #pragma unroll
        for (int j = 0; j < 4; ++j) {
          acc[i][j] = __builtin_amdgcn_mfma_f32_16x16x32_bf16(ah[i], bh[j], acc[i][j], 0, 0, 0);
          acc[i][j] = __builtin_amdgcn_mfma_f32_16x16x32_bf16(ah[i], bl[j], acc[i][j], 0, 0, 0);
          acc[i][j] = __builtin_amdgcn_mfma_f32_16x16x32_bf16(al[i], bh[j], acc[i][j], 0, 0, 0);
        }
    }
    __syncthreads();
  }

  const float* invP = ws_ro + WS_INVP;
  const float* invK = ws_ro + WS_INVK;
  #pragma unroll
  for (int i = 0; i < 4; ++i) {
    #pragma unroll
    for (int q = 0; q < 4; ++q) {
      int row = bm0 + wm * 64 + i * 16 + lg * 4 + q;
      float ip = invP[row];
      #pragma unroll
      for (int j = 0; j < 4; ++j) {
        int col = bn0 + wn * 64 + j * 16 + lr;
        C[(size_t)row * PP + col] = acc[i][j][q] * ip * invK[col];
      }
    }
  }
}

// ---------- Kernel 3: wave-per-row fused exact top-8 + entropy + prompt -----
// Selection = round-3's validated (float,int) argmax; prompt = round-6's
// validated per-wave gather/normalize/write. No barriers, no LDS.
__global__ __launch_bounds__(256) void fused_wave_topk_prompt(
    const float* __restrict__ ppg, const float* __restrict__ pool,
    const float* __restrict__ cw, const float* __restrict__ cb,
    float* __restrict__ ws, float* __restrict__ out) {
  int wid = threadIdx.x >> 6, lane = threadIdx.x & 63;
  int row = blockIdx.x * 4 + wid;
  const float* crow = out + (size_t)row * PP;

  // lane holds 16 values: c[p*4+j] = cos[row][p*256 + lane*4 + j]  (r3 layout)
  float c[16];
  #pragma unroll
  for (int p = 0; p < 4; ++p) {
    f32x4 v = *(const f32x4*)(crow + p * 256 + lane * 4);
    c[p * 4 + 0] = v[0]; c[p * 4 + 1] = v[1]; c[p * 4 + 2] = v[2]; c[p * 4 + 3] = v[3];
  }

  // ---- entropy with fixed shift m=2 (validated r4-r6; exact fp32 source) ----
  {
    float z = 0.f, w = 0.f;
    #pragma unroll
    for (int l = 0; l < 16; ++l) {
      float s = 1.0f - c[l];
      float e = __expf(s - 2.0f);
      z += e; w += s * e;
    }
    #pragma unroll
    for (int o = 1; o < 64; o <<= 1) { z += __shfl_xor(z, o); w += __shfl_xor(w, o); }
    if (lane == 0) ws[WS_ENT + row] = 2.0f + __logf(z) - w / z;
  }

  // ---- exact top-8 by iterative wave argmax (verbatim r3 — validated) ----
  unsigned used = 0;
  float score_sum = 0.f;
  int myidx = 0;
  #pragma unroll
  for (int it = 0; it < KSEL; ++it) {
    float v = -2.0f; int gi = 1 << 30;
    #pragma unroll
    for (int l = 0; l < 16; ++l) {
      if (!((used >> l) & 1u)) {
        float cv = c[l];
        int g = ((l >> 2) << 8) | (lane << 2) | (l & 3);
        if (cv > v || (cv == v && g < gi)) { v = cv; gi = g; }
      }
    }
    #pragma unroll
    for (int o = 1; o < 64; o <<= 1) {
      float ov = __shfl_xor(v, o);
      int og = __shfl_xor(gi, o);
      if (ov > v || (ov == v && og < gi)) { v = ov; gi = og; }
    }
    score_sum += 1.0f - v;
    if (((gi >> 2) & 63) == lane) used |= 1u << ((((gi >> 8) & 3) << 2) | (gi & 3));
    if (lane == it) myidx = gi;
  }
  if (lane == 0) ws[WS_SCORE + row] = score_sum;

  // ---- ppg row into regs (r6 layout: pv[j] = elems j*256 + lane*4) ----
  const float* prow = ppg + (size_t)row * DD;
  f32x4 pv[4];
  #pragma unroll
  for (int j = 0; j < 4; ++j)
    pv[j] = *(const f32x4*)(prow + j * 256 + lane * 4);

  // ---- prompt: gather 8 pool rows (wave-coalesced), conv, mean (r6 code) ----
  float w0 = cw[0], w1 = cw[1], w2 = cw[2], bb = cb[0];
  float a[16] = {};
  #pragma unroll
  for (int s = 0; s < KSEL; ++s) {
    int rj = __shfl(myidx, s);
    const float* src = pool + (size_t)rj * DD;
    #pragma unroll
    for (int j = 0; j < 4; ++j) {
      int d0 = j * 256 + lane * 4;
      f32x4 x = *(const f32x4*)(src + d0);
      float xm = (d0 > 0) ? src[d0 - 1] : 0.f;
      float xp = (d0 + 4 < DD) ? src[d0 + 4] : 0.f;
      float y0 = fmaf(w0, xm,   fmaf(w1, x[0], fmaf(w2, x[1], bb)));
      float y1 = fmaf(w0, x[0], fmaf(w1, x[1], fmaf(w2, x[2], bb)));
      float y2 = fmaf(w0, x[1], fmaf(w1, x[2], fmaf(w2, x[3], bb)));
      float y3 = fmaf(w0, x[2], fmaf(w1, x[3], fmaf(w2, xp,   bb)));
      a[j * 4 + 0] += fmaxf(y0, 0.f);
      a[j * 4 + 1] += fmaxf(y1, 0.f);
      a[j * 4 + 2] += fmaxf(y2, 0.f);
      a[j * 4 + 3] += fmaxf(y3, 0.f);
    }
  }
  #pragma unroll
  for (int l = 0; l < 16; ++l) a[l] *= 0.125f;

  // ---- wave min/max over the 1024 prompt values (r6 code) ----
  float lmin = a[0], lmax = a[0];
  #pragma unroll
  for (int l = 1; l < 16; ++l) { lmin = fminf(lmin, a[l]); lmax = fmaxf(lmax, a[l]); }
  #pragma unroll
  for (int o = 1; o < 64; o <<= 1) {
    lmin = fminf(lmin, __shfl_xor(lmin, o));
    lmax = fmaxf(lmax, __shfl_xor(lmax, o));
  }
  float scale = 2.0f / (lmax - lmin);

  // ---- normalize + add ppg + overwrite this row of out (r6 code) ----
  float* orow = out + (size_t)row * DD;
  #pragma unroll
  for (int j = 0; j < 4; ++j) {
    f32x4 o4;
    #pragma unroll
    for (int q = 0; q < 4; ++q)
      o4[q] = pv[j][q] + (scale * (a[j * 4 + q] - lmin) - 1.0f);
    *(f32x4*)(orow + j * 256 + lane * 4) = o4;
  }
}

// ---------- Kernel 4: deterministic final reduction -------------------------
__global__ __launch_bounds__(256) void finalize_kernel(const float* __restrict__ ws,
                                                       float* __restrict__ out) {
  int t = threadIdx.x;
  const float* ss = ws + WS_SCORE;
  const float* ee = ws + WS_ENT;
  float s = 0.f, e = 0.f;
  for (int i = t; i < BZ; i += 256) { s += ss[i]; e += ee[i]; }
  __shared__ float rs[4], re[4];
  #pragma unroll
  for (int o = 32; o > 0; o >>= 1) { s += __shfl_down(s, o); e += __shfl_down(e, o); }
  if ((t & 63) == 0) { rs[t >> 6] = s; re[t >> 6] = e; }
  __syncthreads();
  if (t == 0) {
    float sT = rs[0] + rs[1] + rs[2] + rs[3];
    float eT = re[0] + re[1] + re[2] + re[3];
    out[(size_t)BZ * DD + 0] = sT / (float)(BZ * KSEL);
    out[(size_t)BZ * DD + 1] = eT / (float)BZ;
  }
}

extern "C" void kernel_launch(void* const* d_in, const int* in_sizes, int n_in,
                              void* d_out, int out_size, void* d_ws, size_t ws_size,
                              hipStream_t stream) {
  const float* ppg  = (const float*)d_in[0];
  const float* keys = (const float*)d_in[1];
  const float* pool = (const float*)d_in[2];
  const float* cw   = (const float*)d_in[3];
  const float* cb   = (const float*)d_in[4];
  float* out = (float*)d_out;
  float* ws  = (float*)d_ws;

  hipLaunchKernelGGL(convert_kernel, dim3(PP + BZ), dim3(256), 0, stream, ppg, keys, ws);
  hipLaunchKernelGGL(gemm_mfma, dim3((BZ / 128) * (PP / 128)), dim3(256), 0, stream, ws, out);
  hipLaunchKernelGGL(fused_wave_topk_prompt, dim3(BZ / 4), dim3(256), 0, stream,
                     ppg, pool, cw, cb, ws, out);
  hipLaunchKernelGGL(finalize_kernel, dim3(1), dim3(256), 0, stream, ws, out);
}

// Round 9
// 135.634 us; speedup vs baseline: 1.5187x; 1.1311x over previous
//
#include <hip/hip_runtime.h>
#include <hip/hip_bf16.h>

#define BZ 8192
#define PP 1024
#define DD 1024
#define KSEL 8

typedef unsigned short u16;
typedef __attribute__((ext_vector_type(8))) short bf16x8;
typedef __attribute__((ext_vector_type(4))) float f32x4;

// ws layout (floats):
//   [0,1024)       inv-norm keys
//   [1024,9216)    inv-norm ppg
//   [9216,17408)   per-row top-8 score sum
//   [17408,25600)  per-row entropy
//   [25600,91136)  top-8 indices (ints)
//   byte 368640 .. : bf16 A_hi, A_lo (16MB each), B_hi, B_lo (2MB each)
// C (fp32 cos matrix) lives in d_out; topk reads it, prompt overwrites it.
#define WS_INVK 0
#define WS_INVP 1024
#define WS_SCORE 9216
#define WS_ENT 17408
#define WS_IDX 25600
#define WS_BF16_BYTE 368640ull

__device__ __forceinline__ u16 f2bf(float x) {
  __hip_bfloat16 h = __float2bfloat16(x);
  return *(u16*)&h;
}
__device__ __forceinline__ float bf2f(u16 u) {
  __hip_bfloat16 h; *(u16*)&h = u;
  return __bfloat162float(h);
}
__device__ __forceinline__ void gll16(const void* g, void* l) {
  __builtin_amdgcn_global_load_lds((__attribute__((address_space(1))) void*)g,
                                   (__attribute__((address_space(3))) void*)l, 16, 0, 0);
}

// ---------- Kernel 1: fused fp32->bf16 hi/lo conversion + inverse norms ------
// (verbatim r3 — validated)
__global__ __launch_bounds__(256) void convert_kernel(const float* __restrict__ ppg,
                                                      const float* __restrict__ keys,
                                                      float* __restrict__ ws) {
  u16* Ahi = (u16*)((char*)ws + WS_BF16_BYTE);
  u16* Alo = Ahi + 8388608;
  u16* Bhi = Alo + 8388608;
  u16* Blo = Bhi + 1048576;

  int blk = blockIdx.x;
  const float* src; u16 *hi, *lo; float* invdst;
  if (blk < PP) {
    src = keys + (size_t)blk * DD;
    hi = Bhi + (size_t)blk * DD; lo = Blo + (size_t)blk * DD;
    invdst = ws + WS_INVK + blk;
  } else {
    int r = blk - PP;
    src = ppg + (size_t)r * DD;
    hi = Ahi + (size_t)r * DD; lo = Alo + (size_t)r * DD;
    invdst = ws + WS_INVP + r;
  }
  int t = threadIdx.x;
  float4 v = ((const float4*)src)[t];
  float x[4] = {v.x, v.y, v.z, v.w};
  u16 h4[4], l4[4];
  float s = 0.f;
  #pragma unroll
  for (int j = 0; j < 4; ++j) {
    h4[j] = f2bf(x[j]);
    l4[j] = f2bf(x[j] - bf2f(h4[j]));
    s += x[j] * x[j];
  }
  *(ushort4*)(hi + t * 4) = *(ushort4*)h4;
  *(ushort4*)(lo + t * 4) = *(ushort4*)l4;

  __shared__ float red[4];
  #pragma unroll
  for (int o = 32; o > 0; o >>= 1) s += __shfl_down(s, o);
  if ((t & 63) == 0) red[t >> 6] = s;
  __syncthreads();
  if (t == 0) {
    float tot = red[0] + red[1] + red[2] + red[3];
    *invdst = 1.0f / fmaxf(sqrtf(tot), 1e-8f);
  }
}

// ---------- Kernel 2: 3-pass bf16 hi/lo MFMA GEMM -> fp32 cos in d_out ------
// (verbatim r3 — validated)
#define LDS_AH 0
#define LDS_AL 8192
#define LDS_BH 16384
#define LDS_BL 24576

__global__ __launch_bounds__(256, 2) void gemm_mfma(const float* __restrict__ ws_ro,
                                                    float* __restrict__ C) {
  const u16* Ahi = (const u16*)((const char*)ws_ro + WS_BF16_BYTE);
  const u16* Alo = Ahi + 8388608;
  const u16* Bhi = Alo + 8388608;
  const u16* Blo = Bhi + 1048576;

  __shared__ u16 lds[32768];  // 64 KB

  int t = threadIdx.x;
  int wid = t >> 6, lane = t & 63;
  int lr = lane & 15, lg = lane >> 4;

  int orig = blockIdx.x;
  int wg = (orig & 7) * 64 + (orig >> 3);
  int bm0 = (wg >> 3) * 128;
  int bn0 = (wg & 7) * 128;
  int wm = wid >> 1, wn = wid & 1;

  size_t offA[4], offB[4];
  int ldso[4];
  #pragma unroll
  for (int r = 0; r < 4; ++r) {
    int s = r * 256 + t;
    int row = s >> 3, g = s & 7;
    offA[r] = (size_t)(bm0 + row) * DD + g * 8;
    offB[r] = (size_t)(bn0 + row) * DD + g * 8;
    ldso[r] = (r * 256 + wid * 64) * 8;
  }

  f32x4 acc[4][4] = {};

  for (int kt = 0; kt < 16; ++kt) {
    int k0 = kt * 64;
    #pragma unroll
    for (int r = 0; r < 4; ++r) {
      gll16(Ahi + offA[r] + k0, &lds[LDS_AH + ldso[r]]);
      gll16(Alo + offA[r] + k0, &lds[LDS_AL + ldso[r]]);
      gll16(Bhi + offB[r] + k0, &lds[LDS_BH + ldso[r]]);
      gll16(Blo + offB[r] + k0, &lds[LDS_BL + ldso[r]]);
    }
    __syncthreads();

    #pragma unroll
    for (int kh = 0; kh < 2; ++kh) {
      bf16x8 ah[4], al[4], bh[4], bl[4];
      #pragma unroll
      for (int i = 0; i < 4; ++i) {
        int off = (wm * 64 + i * 16 + lr) * 64 + kh * 32 + lg * 8;
        ah[i] = *(const bf16x8*)&lds[LDS_AH + off];
        al[i] = *(const bf16x8*)&lds[LDS_AL + off];
      }
      #pragma unroll
      for (int j = 0; j < 4; ++j) {
        int off = (wn * 64 + j * 16 + lr) * 64 + kh * 32 + lg * 8;
        bh[j] = *(const bf16x8*)&lds[LDS_BH + off];
        bl[j] = *(const bf16x8*)&lds[LDS_BL + off];
      }
      #pragma unroll
      for (int i = 0; i < 4; ++i)
        #pragma unroll
        for (int j = 0; j < 4; ++j) {
          acc[i][j] = __builtin_amdgcn_mfma_f32_16x16x32_bf16(ah[i], bh[j], acc[i][j], 0, 0, 0);
          acc[i][j] = __builtin_amdgcn_mfma_f32_16x16x32_bf16(ah[i], bl[j], acc[i][j], 0, 0, 0);
          acc[i][j] = __builtin_amdgcn_mfma_f32_16x16x32_bf16(al[i], bh[j], acc[i][j], 0, 0, 0);
        }
    }
    __syncthreads();
  }

  const float* invP = ws_ro + WS_INVP;
  const float* invK = ws_ro + WS_INVK;
  #pragma unroll
  for (int i = 0; i < 4; ++i) {
    #pragma unroll
    for (int q = 0; q < 4; ++q) {
      int row = bm0 + wm * 64 + i * 16 + lg * 4 + q;
      float ip = invP[row];
      #pragma unroll
      for (int j = 0; j < 4; ++j) {
        int col = bn0 + wn * 64 + j * 16 + lr;
        C[(size_t)row * PP + col] = acc[i][j][q] * ip * invK[col];
      }
    }
  }
}

// ---------- Kernel 3: wave-per-row exact top-8 + entropy (lean, r3 core) ----
__global__ __launch_bounds__(256) void topk_wave_kernel(const float* __restrict__ cosm,
                                                        float* __restrict__ ws) {
  int wid = threadIdx.x >> 6, lane = threadIdx.x & 63;
  int row = blockIdx.x * 4 + wid;
  const float* crow = cosm + (size_t)row * PP;

  // lane holds 16 values: c[p*4+j] = cos[row][p*256 + lane*4 + j]  (r3 layout)
  float c[16];
  #pragma unroll
  for (int p = 0; p < 4; ++p) {
    f32x4 v = *(const f32x4*)(crow + p * 256 + lane * 4);
    c[p * 4 + 0] = v[0]; c[p * 4 + 1] = v[1]; c[p * 4 + 2] = v[2]; c[p * 4 + 3] = v[3];
  }

  // ---- entropy, fixed shift m=2 (validated r6/r8 on exact C) ----
  float z = 0.f, w = 0.f;
  #pragma unroll
  for (int l = 0; l < 16; ++l) {
    float s = 1.0f - c[l];
    float e = __expf(s - 2.0f);
    z += e; w += s * e;
  }
  #pragma unroll
  for (int o = 1; o < 64; o <<= 1) { z += __shfl_xor(z, o); w += __shfl_xor(w, o); }
  if (lane == 0) ws[WS_ENT + row] = 2.0f + __logf(z) - w / z;

  // ---- exact top-8 by iterative wave argmax (verbatim r3 — validated) ----
  unsigned used = 0;
  float score_sum = 0.f;
  int myidx = 0;
  #pragma unroll
  for (int it = 0; it < KSEL; ++it) {
    float v = -2.0f; int gi = 1 << 30;
    #pragma unroll
    for (int l = 0; l < 16; ++l) {
      if (!((used >> l) & 1u)) {
        float cv = c[l];
        int g = ((l >> 2) << 8) | (lane << 2) | (l & 3);
        if (cv > v || (cv == v && g < gi)) { v = cv; gi = g; }
      }
    }
    #pragma unroll
    for (int o = 1; o < 64; o <<= 1) {
      float ov = __shfl_xor(v, o);
      int og = __shfl_xor(gi, o);
      if (ov > v || (ov == v && og < gi)) { v = ov; gi = og; }
    }
    score_sum += 1.0f - v;
    if (((gi >> 2) & 63) == lane) used |= 1u << ((((gi >> 8) & 3) << 2) | (gi & 3));
    if (lane == it) myidx = gi;
  }
  if (lane == 0) ws[WS_SCORE + row] = score_sum;
  if (lane < KSEL) ((int*)(ws + WS_IDX))[row * KSEL + lane] = myidx;
}

// ---------- Kernel 4: block-per-row prompt (r2 core + shuffle halo) ---------
__global__ __launch_bounds__(256) void prompt_kernel(const float* __restrict__ ppg,
                                                     const float* __restrict__ pool,
                                                     const float* __restrict__ cw,
                                                     const float* __restrict__ cb,
                                                     const float* __restrict__ ws,
                                                     float* __restrict__ out) {
  int row = blockIdx.x;
  int t = threadIdx.x;
  int lane = t & 63;
  const int* idx = (const int*)(ws + WS_IDX) + row * KSEL;
  float w0 = cw[0], w1 = cw[1], w2 = cw[2], bb = cb[0];
  int d0 = t * 4;

  float a0 = 0.f, a1 = 0.f, a2 = 0.f, a3 = 0.f;
  #pragma unroll
  for (int j = 0; j < KSEL; ++j) {
    int r = idx[j];
    const float* src = pool + (size_t)r * DD;
    f32x4 x = *(const f32x4*)(src + d0);
    // halo via wave shuffles; only wave-boundary lanes touch memory
    float xm_n = __shfl_up(x[3], 1);
    float xp_n = __shfl_down(x[0], 1);
    float xm, xp;
    if (lane == 0)       xm = (t > 0)   ? src[d0 - 1] : 0.f;
    else                 xm = xm_n;
    if (lane == 63)      xp = (t < 255) ? src[d0 + 4] : 0.f;
    else                 xp = xp_n;
    float y0 = fmaf(w0, xm,   fmaf(w1, x[0], fmaf(w2, x[1], bb)));
    float y1 = fmaf(w0, x[0], fmaf(w1, x[1], fmaf(w2, x[2], bb)));
    float y2 = fmaf(w0, x[1], fmaf(w1, x[2], fmaf(w2, x[3], bb)));
    float y3 = fmaf(w0, x[2], fmaf(w1, x[3], fmaf(w2, xp,   bb)));
    a0 += fmaxf(y0, 0.f);
    a1 += fmaxf(y1, 0.f);
    a2 += fmaxf(y2, 0.f);
    a3 += fmaxf(y3, 0.f);
  }
  a0 *= 0.125f; a1 *= 0.125f; a2 *= 0.125f; a3 *= 0.125f;

  // block min/max over the 1024 prompt values (r2 verbatim)
  __shared__ float rmin[4], rmax[4];
  float lmin = fminf(fminf(a0, a1), fminf(a2, a3));
  float lmax = fmaxf(fmaxf(a0, a1), fmaxf(a2, a3));
  #pragma unroll
  for (int o = 32; o > 0; o >>= 1) {
    lmin = fminf(lmin, __shfl_down(lmin, o));
    lmax = fmaxf(lmax, __shfl_down(lmax, o));
  }
  if ((t & 63) == 0) { rmin[t >> 6] = lmin; rmax[t >> 6] = lmax; }
  __syncthreads();
  float pmin = fminf(fminf(rmin[0], rmin[1]), fminf(rmin[2], rmin[3]));
  float pmax = fmaxf(fmaxf(rmax[0], rmax[1]), fmaxf(rmax[2], rmax[3]));
  float scale = 2.0f / (pmax - pmin);

  f32x4 pv = *(const f32x4*)(ppg + (size_t)row * DD + d0);
  f32x4 o4;
  o4[0] = pv[0] + (scale * (a0 - pmin) - 1.0f);
  o4[1] = pv[1] + (scale * (a1 - pmin) - 1.0f);
  o4[2] = pv[2] + (scale * (a2 - pmin) - 1.0f);
  o4[3] = pv[3] + (scale * (a3 - pmin) - 1.0f);
  *(f32x4*)(out + (size_t)row * DD + d0) = o4;
}

// ---------- Kernel 5: deterministic final reduction -------------------------
__global__ __launch_bounds__(256) void finalize_kernel(const float* __restrict__ ws,
                                                       float* __restrict__ out) {
  int t = threadIdx.x;
  const float* ss = ws + WS_SCORE;
  const float* ee = ws + WS_ENT;
  float s = 0.f, e = 0.f;
  for (int i = t; i < BZ; i += 256) { s += ss[i]; e += ee[i]; }
  __shared__ float rs[4], re[4];
  #pragma unroll
  for (int o = 32; o > 0; o >>= 1) { s += __shfl_down(s, o); e += __shfl_down(e, o); }
  if ((t & 63) == 0) { rs[t >> 6] = s; re[t >> 6] = e; }
  __syncthreads();
  if (t == 0) {
    float sT = rs[0] + rs[1] + rs[2] + rs[3];
    float eT = re[0] + re[1] + re[2] + re[3];
    out[(size_t)BZ * DD + 0] = sT / (float)(BZ * KSEL);
    out[(size_t)BZ * DD + 1] = eT / (float)BZ;
  }
}

extern "C" void kernel_launch(void* const* d_in, const int* in_sizes, int n_in,
                              void* d_out, int out_size, void* d_ws, size_t ws_size,
                              hipStream_t stream) {
  const float* ppg  = (const float*)d_in[0];
  const float* keys = (const float*)d_in[1];
  const float* pool = (const float*)d_in[2];
  const float* cw   = (const float*)d_in[3];
  const float* cb   = (const float*)d_in[4];
  float* out = (float*)d_out;
  float* ws  = (float*)d_ws;

  hipLaunchKernelGGL(convert_kernel, dim3(PP + BZ), dim3(256), 0, stream, ppg, keys, ws);
  hipLaunchKernelGGL(gemm_mfma, dim3((BZ / 128) * (PP / 128)), dim3(256), 0, stream, ws, out);
  hipLaunchKernelGGL(topk_wave_kernel, dim3(BZ / 4), dim3(256), 0, stream, out, ws);
  hipLaunchKernelGGL(prompt_kernel, dim3(BZ), dim3(256), 0, stream, ppg, pool, cw, cb, ws, out);
  hipLaunchKernelGGL(finalize_kernel, dim3(1), dim3(256), 0, stream, ws, out);
}

// Round 10
// 135.634 us; speedup vs baseline: 1.5187x; 1.0000x over previous
//
#include <hip/hip_runtime.h>
#include <hip/hip_bf16.h>

#define BZ 8192
#define PP 1024
#define DD 1024
#define KSEL 8

typedef unsigned short u16;
typedef __attribute__((ext_vector_type(8))) short bf16x8;
typedef __attribute__((ext_vector_type(4))) float f32x4;

// ws layout (floats):
//   [0,1024)       inv-norm keys
//   [1024,9216)    inv-norm ppg
//   [9216,17408)   per-row top-8 score sum
//   [17408,25600)  per-row entropy
//   [25600,91136)  top-8 indices (ints)
//   byte 368640 .. : bf16 A_hi, A_lo (16MB each), B_hi, B_lo (2MB each)
// C (fp32 cos matrix) lives in d_out; topk reads it, prompt overwrites it.
#define WS_INVK 0
#define WS_INVP 1024
#define WS_SCORE 9216
#define WS_ENT 17408
#define WS_IDX 25600
#define WS_BF16_BYTE 368640ull

__device__ __forceinline__ u16 f2bf(float x) {
  __hip_bfloat16 h = __float2bfloat16(x);
  return *(u16*)&h;
}
__device__ __forceinline__ float bf2f(u16 u) {
  __hip_bfloat16 h; *(u16*)&h = u;
  return __bfloat162float(h);
}
__device__ __forceinline__ void gll16(const void* g, void* l) {
  __builtin_amdgcn_global_load_lds((__attribute__((address_space(1))) void*)g,
                                   (__attribute__((address_space(3))) void*)l, 16, 0, 0);
}

// ---------- Kernel 1: fused fp32->bf16 hi/lo conversion + inverse norms ------
// (verbatim r3 — validated)
__global__ __launch_bounds__(256) void convert_kernel(const float* __restrict__ ppg,
                                                      const float* __restrict__ keys,
                                                      float* __restrict__ ws) {
  u16* Ahi = (u16*)((char*)ws + WS_BF16_BYTE);
  u16* Alo = Ahi + 8388608;
  u16* Bhi = Alo + 8388608;
  u16* Blo = Bhi + 1048576;

  int blk = blockIdx.x;
  const float* src; u16 *hi, *lo; float* invdst;
  if (blk < PP) {
    src = keys + (size_t)blk * DD;
    hi = Bhi + (size_t)blk * DD; lo = Blo + (size_t)blk * DD;
    invdst = ws + WS_INVK + blk;
  } else {
    int r = blk - PP;
    src = ppg + (size_t)r * DD;
    hi = Ahi + (size_t)r * DD; lo = Alo + (size_t)r * DD;
    invdst = ws + WS_INVP + r;
  }
  int t = threadIdx.x;
  float4 v = ((const float4*)src)[t];
  float x[4] = {v.x, v.y, v.z, v.w};
  u16 h4[4], l4[4];
  float s = 0.f;
  #pragma unroll
  for (int j = 0; j < 4; ++j) {
    h4[j] = f2bf(x[j]);
    l4[j] = f2bf(x[j] - bf2f(h4[j]));
    s += x[j] * x[j];
  }
  *(ushort4*)(hi + t * 4) = *(ushort4*)h4;
  *(ushort4*)(lo + t * 4) = *(ushort4*)l4;

  __shared__ float red[4];
  #pragma unroll
  for (int o = 32; o > 0; o >>= 1) s += __shfl_down(s, o);
  if ((t & 63) == 0) red[t >> 6] = s;
  __syncthreads();
  if (t == 0) {
    float tot = red[0] + red[1] + red[2] + red[3];
    *invdst = 1.0f / fmaxf(sqrtf(tot), 1e-8f);
  }
}

// ---------- Kernel 2: 3-pass bf16 hi/lo MFMA GEMM -> fp32 cos in d_out ------
// (verbatim r3 — validated). Note: row-panel p of C is written entirely by
// blocks with orig&7 == p>>3 -> lives in that XCD's L2 (512 KB/panel).
#define LDS_AH 0
#define LDS_AL 8192
#define LDS_BH 16384
#define LDS_BL 24576

__global__ __launch_bounds__(256, 2) void gemm_mfma(const float* __restrict__ ws_ro,
                                                    float* __restrict__ C) {
  const u16* Ahi = (const u16*)((const char*)ws_ro + WS_BF16_BYTE);
  const u16* Alo = Ahi + 8388608;
  const u16* Bhi = Alo + 8388608;
  const u16* Blo = Bhi + 1048576;

  __shared__ u16 lds[32768];  // 64 KB

  int t = threadIdx.x;
  int wid = t >> 6, lane = t & 63;
  int lr = lane & 15, lg = lane >> 4;

  int orig = blockIdx.x;
  int wg = (orig & 7) * 64 + (orig >> 3);
  int bm0 = (wg >> 3) * 128;
  int bn0 = (wg & 7) * 128;
  int wm = wid >> 1, wn = wid & 1;

  size_t offA[4], offB[4];
  int ldso[4];
  #pragma unroll
  for (int r = 0; r < 4; ++r) {
    int s = r * 256 + t;
    int row = s >> 3, g = s & 7;
    offA[r] = (size_t)(bm0 + row) * DD + g * 8;
    offB[r] = (size_t)(bn0 + row) * DD + g * 8;
    ldso[r] = (r * 256 + wid * 64) * 8;
  }

  f32x4 acc[4][4] = {};

  for (int kt = 0; kt < 16; ++kt) {
    int k0 = kt * 64;
    #pragma unroll
    for (int r = 0; r < 4; ++r) {
      gll16(Ahi + offA[r] + k0, &lds[LDS_AH + ldso[r]]);
      gll16(Alo + offA[r] + k0, &lds[LDS_AL + ldso[r]]);
      gll16(Bhi + offB[r] + k0, &lds[LDS_BH + ldso[r]]);
      gll16(Blo + offB[r] + k0, &lds[LDS_BL + ldso[r]]);
    }
    __syncthreads();

    #pragma unroll
    for (int kh = 0; kh < 2; ++kh) {
      bf16x8 ah[4], al[4], bh[4], bl[4];
      #pragma unroll
      for (int i = 0; i < 4; ++i) {
        int off = (wm * 64 + i * 16 + lr) * 64 + kh * 32 + lg * 8;
        ah[i] = *(const bf16x8*)&lds[LDS_AH + off];
        al[i] = *(const bf16x8*)&lds[LDS_AL + off];
      }
      #pragma unroll
      for (int j = 0; j < 4; ++j) {
        int off = (wn * 64 + j * 16 + lr) * 64 + kh * 32 + lg * 8;
        bh[j] = *(const bf16x8*)&lds[LDS_BH + off];
        bl[j] = *(const bf16x8*)&lds[LDS_BL + off];
      }
      #pragma unroll
      for (int i = 0; i < 4; ++i)
        #pragma unroll
        for (int j = 0; j < 4; ++j) {
          acc[i][j] = __builtin_amdgcn_mfma_f32_16x16x32_bf16(ah[i], bh[j], acc[i][j], 0, 0, 0);
          acc[i][j] = __builtin_amdgcn_mfma_f32_16x16x32_bf16(ah[i], bl[j], acc[i][j], 0, 0, 0);
          acc[i][j] = __builtin_amdgcn_mfma_f32_16x16x32_bf16(al[i], bh[j], acc[i][j], 0, 0, 0);
        }
    }
    __syncthreads();
  }

  const float* invP = ws_ro + WS_INVP;
  const float* invK = ws_ro + WS_INVK;
  #pragma unroll
  for (int i = 0; i < 4; ++i) {
    #pragma unroll
    for (int q = 0; q < 4; ++q) {
      int row = bm0 + wm * 64 + i * 16 + lg * 4 + q;
      float ip = invP[row];
      #pragma unroll
      for (int j = 0; j < 4; ++j) {
        int col = bn0 + wn * 64 + j * 16 + lr;
        C[(size_t)row * PP + col] = acc[i][j][q] * ip * invK[col];
      }
    }
  }
}

// ---------- Kernel 3: wave-per-row exact top-8 + entropy (XCD-local rows) ---
// Row remap: blocks with orig&7 == x read rows [x*1024, (x+1)*1024) — the
// panels XCD x's L2 already holds from the gemm (round-robin dispatch).
__global__ __launch_bounds__(256) void topk_wave_kernel(const float* __restrict__ cosm,
                                                        float* __restrict__ ws) {
  int wid = threadIdx.x >> 6, lane = threadIdx.x & 63;
  int orig = blockIdx.x;
  int row = ((orig & 7) << 10) + ((orig >> 3) << 2) + wid;
  const float* crow = cosm + (size_t)row * PP;

  // lane holds 16 values: c[p*4+j] = cos[row][p*256 + lane*4 + j]  (r3 layout)
  float c[16];
  #pragma unroll
  for (int p = 0; p < 4; ++p) {
    f32x4 v = *(const f32x4*)(crow + p * 256 + lane * 4);
    c[p * 4 + 0] = v[0]; c[p * 4 + 1] = v[1]; c[p * 4 + 2] = v[2]; c[p * 4 + 3] = v[3];
  }

  // ---- entropy, fixed shift m=2 (validated r6/r8/r9 on exact C) ----
  float z = 0.f, w = 0.f;
  #pragma unroll
  for (int l = 0; l < 16; ++l) {
    float s = 1.0f - c[l];
    float e = __expf(s - 2.0f);
    z += e; w += s * e;
  }
  #pragma unroll
  for (int o = 1; o < 64; o <<= 1) { z += __shfl_xor(z, o); w += __shfl_xor(w, o); }
  if (lane == 0) ws[WS_ENT + row] = 2.0f + __logf(z) - w / z;

  // ---- exact top-8 by iterative wave argmax (verbatim r3 — validated) ----
  unsigned used = 0;
  float score_sum = 0.f;
  int myidx = 0;
  #pragma unroll
  for (int it = 0; it < KSEL; ++it) {
    float v = -2.0f; int gi = 1 << 30;
    #pragma unroll
    for (int l = 0; l < 16; ++l) {
      if (!((used >> l) & 1u)) {
        float cv = c[l];
        int g = ((l >> 2) << 8) | (lane << 2) | (l & 3);
        if (cv > v || (cv == v && g < gi)) { v = cv; gi = g; }
      }
    }
    #pragma unroll
    for (int o = 1; o < 64; o <<= 1) {
      float ov = __shfl_xor(v, o);
      int og = __shfl_xor(gi, o);
      if (ov > v || (ov == v && og < gi)) { v = ov; gi = og; }
    }
    score_sum += 1.0f - v;
    if (((gi >> 2) & 63) == lane) used |= 1u << ((((gi >> 8) & 3) << 2) | (gi & 3));
    if (lane == it) myidx = gi;
  }
  if (lane == 0) ws[WS_SCORE + row] = score_sum;
  if (lane < KSEL) ((int*)(ws + WS_IDX))[row * KSEL + lane] = myidx;
}

// ---------- Kernel 4: block-per-row prompt (r9 validated + XCD-local rows) --
__global__ __launch_bounds__(256) void prompt_kernel(const float* __restrict__ ppg,
                                                     const float* __restrict__ pool,
                                                     const float* __restrict__ cw,
                                                     const float* __restrict__ cb,
                                                     const float* __restrict__ ws,
                                                     float* __restrict__ out) {
  int orig = blockIdx.x;
  int row = ((orig & 7) << 10) + (orig >> 3);
  int t = threadIdx.x;
  int lane = t & 63;
  const int* idx = (const int*)(ws + WS_IDX) + row * KSEL;
  float w0 = cw[0], w1 = cw[1], w2 = cw[2], bb = cb[0];
  int d0 = t * 4;

  float a0 = 0.f, a1 = 0.f, a2 = 0.f, a3 = 0.f;
  #pragma unroll
  for (int j = 0; j < KSEL; ++j) {
    int r = idx[j];
    const float* src = pool + (size_t)r * DD;
    f32x4 x = *(const f32x4*)(src + d0);
    // halo via wave shuffles; only wave-boundary lanes touch memory
    float xm_n = __shfl_up(x[3], 1);
    float xp_n = __shfl_down(x[0], 1);
    float xm, xp;
    if (lane == 0)       xm = (t > 0)   ? src[d0 - 1] : 0.f;
    else                 xm = xm_n;
    if (lane == 63)      xp = (t < 255) ? src[d0 + 4] : 0.f;
    else                 xp = xp_n;
    float y0 = fmaf(w0, xm,   fmaf(w1, x[0], fmaf(w2, x[1], bb)));
    float y1 = fmaf(w0, x[0], fmaf(w1, x[1], fmaf(w2, x[2], bb)));
    float y2 = fmaf(w0, x[1], fmaf(w1, x[2], fmaf(w2, x[3], bb)));
    float y3 = fmaf(w0, x[2], fmaf(w1, x[3], fmaf(w2, xp,   bb)));
    a0 += fmaxf(y0, 0.f);
    a1 += fmaxf(y1, 0.f);
    a2 += fmaxf(y2, 0.f);
    a3 += fmaxf(y3, 0.f);
  }
  a0 *= 0.125f; a1 *= 0.125f; a2 *= 0.125f; a3 *= 0.125f;

  // block min/max over the 1024 prompt values (r2 verbatim)
  __shared__ float rmin[4], rmax[4];
  float lmin = fminf(fminf(a0, a1), fminf(a2, a3));
  float lmax = fmaxf(fmaxf(a0, a1), fmaxf(a2, a3));
  #pragma unroll
  for (int o = 32; o > 0; o >>= 1) {
    lmin = fminf(lmin, __shfl_down(lmin, o));
    lmax = fmaxf(lmax, __shfl_down(lmax, o));
  }
  if ((t & 63) == 0) { rmin[t >> 6] = lmin; rmax[t >> 6] = lmax; }
  __syncthreads();
  float pmin = fminf(fminf(rmin[0], rmin[1]), fminf(rmin[2], rmin[3]));
  float pmax = fmaxf(fmaxf(rmax[0], rmax[1]), fmaxf(rmax[2], rmax[3]));
  float scale = 2.0f / (pmax - pmin);

  f32x4 pv = *(const f32x4*)(ppg + (size_t)row * DD + d0);
  f32x4 o4;
  o4[0] = pv[0] + (scale * (a0 - pmin) - 1.0f);
  o4[1] = pv[1] + (scale * (a1 - pmin) - 1.0f);
  o4[2] = pv[2] + (scale * (a2 - pmin) - 1.0f);
  o4[3] = pv[3] + (scale * (a3 - pmin) - 1.0f);
  *(f32x4*)(out + (size_t)row * DD + d0) = o4;
}

// ---------- Kernel 5: deterministic final reduction -------------------------
__global__ __launch_bounds__(256) void finalize_kernel(const float* __restrict__ ws,
                                                       float* __restrict__ out) {
  int t = threadIdx.x;
  const float* ss = ws + WS_SCORE;
  const float* ee = ws + WS_ENT;
  float s = 0.f, e = 0.f;
  for (int i = t; i < BZ; i += 256) { s += ss[i]; e += ee[i]; }
  __shared__ float rs[4], re[4];
  #pragma unroll
  for (int o = 32; o > 0; o >>= 1) { s += __shfl_down(s, o); e += __shfl_down(e, o); }
  if ((t & 63) == 0) { rs[t >> 6] = s; re[t >> 6] = e; }
  __syncthreads();
  if (t == 0) {
    float sT = rs[0] + rs[1] + rs[2] + rs[3];
    float eT = re[0] + re[1] + re[2] + re[3];
    out[(size_t)BZ * DD + 0] = sT / (float)(BZ * KSEL);
    out[(size_t)BZ * DD + 1] = eT / (float)BZ;
  }
}

extern "C" void kernel_launch(void* const* d_in, const int* in_sizes, int n_in,
                              void* d_out, int out_size, void* d_ws, size_t ws_size,
                              hipStream_t stream) {
  const float* ppg  = (const float*)d_in[0];
  const float* keys = (const float*)d_in[1];
  const float* pool = (const float*)d_in[2];
  const float* cw   = (const float*)d_in[3];
  const float* cb   = (const float*)d_in[4];
  float* out = (float*)d_out;
  float* ws  = (float*)d_ws;

  hipLaunchKernelGGL(convert_kernel, dim3(PP + BZ), dim3(256), 0, stream, ppg, keys, ws);
  hipLaunchKernelGGL(gemm_mfma, dim3((BZ / 128) * (PP / 128)), dim3(256), 0, stream, ws, out);
  hipLaunchKernelGGL(topk_wave_kernel, dim3(BZ / 4), dim3(256), 0, stream, out, ws);
  hipLaunchKernelGGL(prompt_kernel, dim3(BZ), dim3(256), 0, stream, ppg, pool, cw, cb, ws, out);
  hipLaunchKernelGGL(finalize_kernel, dim3(1), dim3(256), 0, stream, ws, out);
}